// Round 3
// baseline (2019.093 us; speedup 1.0000x reference)
//
#include <hip/hip_runtime.h>
#include <cstddef>

// Decoder tree-GRU, MI355X gfx950. B=32768, I=H=128, O=32, DEPTH=5, ARITY=2.
// Single persistent-weight kernel: each block owns 64 batch rows for the whole
// 63-node preorder tree. Weights live in VGPRs (184/wave), probs stack in LDS,
// hidden stack in global ws (L2/L3 resident). 2 dispatches total.

#define BATCH 32768

typedef float f32x4 __attribute__((ext_vector_type(4)));
typedef short s16x8 __attribute__((ext_vector_type(8)));
typedef unsigned short u16;

__device__ __forceinline__ float bf2f(u16 u){unsigned x=((unsigned)u)<<16;return __builtin_bit_cast(float,x);}
__device__ __forceinline__ u16 f2bf(float f){unsigned u=__builtin_bit_cast(unsigned,f);u+=0x7fffu+((u>>16)&1u);return (u16)(u>>16);}
__device__ __forceinline__ float sigm(float x){return 1.f/(1.f+__expf(-x));}
__device__ __forceinline__ float tanhf_(float x){return 1.f-2.f/(__expf(2.f*x)+1.f);}
__device__ __forceinline__ f32x4 mf(s16x8 a,s16x8 b,f32x4 c){return __builtin_amdgcn_mfma_f32_16x16x32_bf16(a,b,c,0,0,0);}

// Preorder schedule: step i (0-based) produces node i+1. byte = lev | (FRAT<<3).
__device__ __constant__ unsigned char SCHED[62] = {
 5,4,3,2,1,9,10,1,9,11,2,1,9,10,1,9,12,3,2,1,9,10,1,9,11,2,1,9,10,1,9,13,
 4,3,2,1,9,10,1,9,11,2,1,9,10,1,9,12,3,2,1,9,10,1,9,11,2,1,9,10,1,9};

// ---------------- prep: pack weights transposed [N][K] bf16 + fused biases ----
// Wz[128][128]=z2h_w^T ; Wo[32][128]=h2o_w^T
// Wcat[512][160]: rows 0-255 gates r,z (k<32: wi[g], k>=32: wh[g]);
//                 rows 256-383 gi_n (k<32: wi[2], else 0);
//                 rows 384-511 gh_n (k<32: 0, else wh[2])
// Wu[128][256]: k<128 uf_w^T, k>=128 ua_w^T
// Bg*[4][128] = {bi0+bh0, bi1+bh1, bi2, bh2} ; Bu[128]=uf_b+ua_b
__global__ void prep_kernel(const float* __restrict__ z2h_w, const float* __restrict__ h2o_w,
                            const float* __restrict__ anc_wi, const float* __restrict__ anc_wh,
                            const float* __restrict__ frat_wi, const float* __restrict__ frat_wh,
                            const float* __restrict__ ua_w, const float* __restrict__ uf_w,
                            const float* __restrict__ anc_bi, const float* __restrict__ anc_bh,
                            const float* __restrict__ frat_bi, const float* __restrict__ frat_bh,
                            const float* __restrict__ ua_b, const float* __restrict__ uf_b,
                            u16* __restrict__ Wz, u16* __restrict__ Wo, u16* __restrict__ Wanc,
                            u16* __restrict__ Wfrat, u16* __restrict__ Wu,
                            float* __restrict__ Bga, float* __restrict__ Bgf, float* __restrict__ Bu) {
  int tid = blockIdx.x * blockDim.x + threadIdx.x;
  int stride = gridDim.x * blockDim.x;
  for (int i = tid; i < 128 * 128; i += stride) {
    int n = i / 128, k = i % 128;
    Wz[n * 128 + k] = f2bf(z2h_w[k * 128 + n]);
  }
  for (int i = tid; i < 32 * 128; i += stride) {
    int n = i / 128, k = i % 128;
    Wo[n * 128 + k] = f2bf(h2o_w[k * 32 + n]);
  }
  for (int i = tid; i < 512 * 160; i += stride) {
    int n = i / 160, k = i % 160;
    float va, vf;
    if (n < 256) {
      int g = n >> 7, hcc = n & 127;
      if (k < 32) { va = anc_wi[g*32*128 + k*128 + hcc]; vf = frat_wi[g*32*128 + k*128 + hcc]; }
      else        { va = anc_wh[g*128*128 + (k-32)*128 + hcc]; vf = frat_wh[g*128*128 + (k-32)*128 + hcc]; }
    } else if (n < 384) {
      int hcc = n - 256;
      if (k < 32) { va = anc_wi[2*32*128 + k*128 + hcc]; vf = frat_wi[2*32*128 + k*128 + hcc]; }
      else        { va = 0.f; vf = 0.f; }
    } else {
      int hcc = n - 384;
      if (k < 32) { va = 0.f; vf = 0.f; }
      else        { va = anc_wh[2*128*128 + (k-32)*128 + hcc]; vf = frat_wh[2*128*128 + (k-32)*128 + hcc]; }
    }
    Wanc[i] = f2bf(va);
    Wfrat[i] = f2bf(vf);
  }
  for (int i = tid; i < 128 * 256; i += stride) {
    int n = i / 256, k = i % 256;
    float v = (k < 128) ? uf_w[k * 128 + n] : ua_w[(k - 128) * 128 + n];
    Wu[i] = f2bf(v);
  }
  for (int i = tid; i < 128; i += stride) {
    Bga[i]       = anc_bi[i]       + anc_bh[i];
    Bga[128 + i] = anc_bi[128 + i] + anc_bh[128 + i];
    Bga[256 + i] = anc_bi[256 + i];
    Bga[384 + i] = anc_bh[256 + i];
    Bgf[i]       = frat_bi[i]       + frat_bh[i];
    Bgf[128 + i] = frat_bi[128 + i] + frat_bh[128 + i];
    Bgf[256 + i] = frat_bi[256 + i];
    Bgf[384 + i] = frat_bh[256 + i];
    Bu[i] = uf_b[i] + ua_b[i];
  }
}

// --------------------------- persistent tree kernel ---------------------------
__global__ __launch_bounds__(512, 4) void tree_kernel(
    const float* __restrict__ z,
    const u16* __restrict__ Wz, const u16* __restrict__ Wo,
    const u16* __restrict__ Wanc, const u16* __restrict__ Wfrat, const u16* __restrict__ Wu,
    const float* __restrict__ Bga, const float* __restrict__ Bgf, const float* __restrict__ Bu,
    const float* __restrict__ z2h_b, const float* __restrict__ h2o_b,
    u16* __restrict__ Gb, float* __restrict__ out) {
  // R: two 64x136 bf16 h-buffers (A1h / H2, swapped each step); A2 [64][264]
  // overlays R[0..16896) during FRAT. PRs: 6-level probs stack [64][40] each.
  __shared__ u16 R[17408];
  __shared__ u16 PRs[15360];
  const int tid = threadIdx.x;
  const int w = tid >> 6, l = tid & 63, lr = l & 15, lq = l >> 4, lk = lq * 8;
  const int hc = 16 * w + lr;         // this lane's hidden column (8-way N split)
  const size_t brow = (size_t)blockIdx.x * 64;
  const size_t GSTR = (size_t)BATCH * 128;

  // ---- persistent weight fragments ----
  s16x8 FA[15], FF[15], FU[8], FO[8];
#pragma unroll
  for (int j = 0; j < 15; ++j) {
    const int gb = (j < 5) ? 0 : ((j < 10) ? 1 : ((j < 11) ? 2 : 3));
    const int ks = (j < 5) ? j : ((j < 10) ? (j - 5) : ((j < 11) ? 0 : (j - 10)));
    const size_t off = (size_t)(128 * gb + hc) * 160 + ks * 32 + lk;
    FA[j] = *(const s16x8*)&Wanc[off];
    FF[j] = *(const s16x8*)&Wfrat[off];
  }
#pragma unroll
  for (int ks = 0; ks < 8; ++ks) FU[ks] = *(const s16x8*)&Wu[(size_t)hc * 256 + ks * 32 + lk];
#pragma unroll
  for (int j = 0; j < 8; ++j) {
    const int nt = j >> 2, ks = j & 3;
    FO[j] = *(const s16x8*)&Wo[(size_t)(16 * nt + lr) * 128 + ks * 32 + lk];
  }
  const float ba0 = Bga[hc], ba1 = Bga[128 + hc], ba2 = Bga[256 + hc], ba3 = Bga[384 + hc];
  const float bf0 = Bgf[hc], bf1 = Bgf[128 + hc], bf2 = Bgf[256 + hc], bf3 = Bgf[384 + hc];
  const float bub = Bu[hc];
  const float bz = z2h_b[hc];
  const float bo0 = h2o_b[lr], bo1 = h2o_b[16 + lr];

  int a1 = 0, h2 = 8704;  // u16 offsets of the two h-buffers in R

  // pred + softmax (waves 4-7) and H2->G copy (waves 0-3), then caller barriers.
  auto pred_phase = [&](int node, int levC, bool doG, u16* Gdst, int hb) {
    if (w >= 4) {
      const int m = w - 4;
      f32x4 p0 = {}, p1 = {};
#pragma unroll
      for (int ks = 0; ks < 4; ++ks) {
        s16x8 a = *(const s16x8*)&R[hb + (16 * m + lr) * 136 + ks * 32 + lk];
        p0 = mf(a, FO[ks], p0);
        p1 = mf(a, FO[4 + ks], p1);
      }
      float* op = out + ((size_t)node * BATCH + brow) * 32;
#pragma unroll
      for (int r = 0; r < 4; ++r) {
        int row = 16 * m + lq * 4 + r;
        float v0 = p0[r] + bo0, v1 = p1[r] + bo1;
        op[row * 32 + lr] = v0;
        op[row * 32 + 16 + lr] = v1;
        float mx = fmaxf(v0, v1);
#pragma unroll
        for (int o = 1; o < 16; o <<= 1) mx = fmaxf(mx, __shfl_xor(mx, o));
        float e0 = __expf(v0 - mx), e1 = __expf(v1 - mx);
        float s = e0 + e1;
#pragma unroll
        for (int o = 1; o < 16; o <<= 1) s += __shfl_xor(s, o);
        float inv = 1.f / s;
        PRs[levC * 2560 + row * 40 + lr] = f2bf(e0 * inv);
        PRs[levC * 2560 + row * 40 + 16 + lr] = f2bf(e1 * inv);
      }
    } else if (doG) {
#pragma unroll
      for (int j = 0; j < 4; ++j) {
        int chunk = (w * 64 + l) + 256 * j, row = chunk >> 4, co = (chunk & 15) * 8;
        *(s16x8*)&Gdst[(brow + row) * 128 + co] = *(const s16x8*)&R[hb + row * 136 + co];
      }
    }
  };

  // ---------------- init: h0 = z@Wz+b -> H2, G[5]; pred node 0 ----------------
  {
    int row = tid >> 3, seg = tid & 7;
    const float* src = z + (brow + row) * 128 + seg * 16;
    u16* dst = &R[a1 + row * 136 + seg * 16];
#pragma unroll
    for (int k = 0; k < 16; ++k) dst[k] = f2bf(src[k]);
  }
  __syncthreads();
  {
    f32x4 acc0[4] = {};
#pragma unroll
    for (int ks = 0; ks < 4; ++ks) {
      s16x8 b = *(const s16x8*)&Wz[(size_t)hc * 128 + ks * 32 + lk];
      s16x8 a[4];
#pragma unroll
      for (int mt = 0; mt < 4; ++mt) a[mt] = *(const s16x8*)&R[a1 + (16 * mt + lr) * 136 + ks * 32 + lk];
#pragma unroll
      for (int mt = 0; mt < 4; ++mt) acc0[mt] = mf(a[mt], b, acc0[mt]);
    }
#pragma unroll
    for (int mt = 0; mt < 4; ++mt)
#pragma unroll
      for (int r = 0; r < 4; ++r) {
        int row = 16 * mt + lq * 4 + r;
        R[h2 + row * 136 + hc] = f2bf(acc0[mt][r] + bz);
      }
  }
  __syncthreads();
  pred_phase(0, 5, true, Gb + 4 * GSTR, h2);
  __syncthreads();
  { int t = a1; a1 = h2; h2 = t; }

  // ------------------------------- 62 tree steps ------------------------------
  for (int i = 0; i < 62; ++i) {
    const int sc = SCHED[i];
    const int lev = sc & 7;
    const bool isF = (sc & 8) != 0;
    const int node = i + 1;
    u16* Glm1 = Gb + (size_t)((lev >= 2) ? (lev - 2) : 0) * GSTR;  // G[lev-1]
    u16* Glv  = Gb + (size_t)(lev - 1) * GSTR;                      // G[lev]

    if (!isF) {
      // ====== ANC: h in A1h (prev H2), probs in PR[lev] -> h_ai ======
      f32x4 acc[4][4] = {};  // [gate gb][mt]
      {
        s16x8 a[4];
#pragma unroll
        for (int mt = 0; mt < 4; ++mt) a[mt] = *(const s16x8*)&PRs[lev * 2560 + (16 * mt + lr) * 40 + lk];
#pragma unroll
        for (int mt = 0; mt < 4; ++mt) {
          acc[0][mt] = mf(a[mt], FA[0], acc[0][mt]);
          acc[1][mt] = mf(a[mt], FA[5], acc[1][mt]);
          acc[2][mt] = mf(a[mt], FA[10], acc[2][mt]);
        }
      }
#pragma unroll
      for (int ks = 1; ks < 5; ++ks) {
        s16x8 a[4];
#pragma unroll
        for (int mt = 0; mt < 4; ++mt) a[mt] = *(const s16x8*)&R[a1 + (16 * mt + lr) * 136 + (ks - 1) * 32 + lk];
#pragma unroll
        for (int mt = 0; mt < 4; ++mt) {
          acc[0][mt] = mf(a[mt], FA[ks], acc[0][mt]);
          acc[1][mt] = mf(a[mt], FA[5 + ks], acc[1][mt]);
          acc[3][mt] = mf(a[mt], FA[10 + ks], acc[3][mt]);
        }
      }
#pragma unroll
      for (int mt = 0; mt < 4; ++mt)
#pragma unroll
        for (int r = 0; r < 4; ++r) {
          int row = 16 * mt + lq * 4 + r;
          float rr = sigm(acc[0][mt][r] + ba0);
          float zz = sigm(acc[1][mt][r] + ba1);
          float nn = tanhf_(acc[2][mt][r] + ba2 + rr * (acc[3][mt][r] + ba3));
          float hold = bf2f(R[a1 + row * 136 + hc]);
          R[h2 + row * 136 + hc] = f2bf((1.f - zz) * nn + zz * hold);
        }
      __syncthreads();
      pred_phase(node, lev - 1, lev >= 2, Glm1, h2);
      __syncthreads();
    } else {
      // ====== FRAT: h_f = GRU(PR[lev-1], h_ai); h2n = tanh(h_f@uf + h@ua) ======
      s16x8 hstage[2];  // prefetch h = G[lev] for the ua matmul
#pragma unroll
      for (int j = 0; j < 2; ++j) {
        int chunk = tid * 2 + j, row = chunk >> 4, co = (chunk & 15) * 8;
        hstage[j] = *(const s16x8*)&Glv[(brow + row) * 128 + co];
      }
      if (lev >= 2) {  // h_ai not in LDS: stage from G[lev-1]
#pragma unroll
        for (int j = 0; j < 2; ++j) {
          int chunk = tid * 2 + j, row = chunk >> 4, co = (chunk & 15) * 8;
          *(s16x8*)&R[a1 + row * 136 + co] = *(const s16x8*)&Glm1[(brow + row) * 128 + co];
        }
      }
      __syncthreads();
      u16 hfbuf[16];
      {
        f32x4 acc[4][4] = {};
        {
          s16x8 a[4];
#pragma unroll
          for (int mt = 0; mt < 4; ++mt) a[mt] = *(const s16x8*)&PRs[(lev - 1) * 2560 + (16 * mt + lr) * 40 + lk];
#pragma unroll
          for (int mt = 0; mt < 4; ++mt) {
            acc[0][mt] = mf(a[mt], FF[0], acc[0][mt]);
            acc[1][mt] = mf(a[mt], FF[5], acc[1][mt]);
            acc[2][mt] = mf(a[mt], FF[10], acc[2][mt]);
          }
        }
#pragma unroll
        for (int ks = 1; ks < 5; ++ks) {
          s16x8 a[4];
#pragma unroll
          for (int mt = 0; mt < 4; ++mt) a[mt] = *(const s16x8*)&R[a1 + (16 * mt + lr) * 136 + (ks - 1) * 32 + lk];
#pragma unroll
          for (int mt = 0; mt < 4; ++mt) {
            acc[0][mt] = mf(a[mt], FF[ks], acc[0][mt]);
            acc[1][mt] = mf(a[mt], FF[5 + ks], acc[1][mt]);
            acc[3][mt] = mf(a[mt], FF[10 + ks], acc[3][mt]);
          }
        }
#pragma unroll
        for (int mt = 0; mt < 4; ++mt)
#pragma unroll
          for (int r = 0; r < 4; ++r) {
            int row = 16 * mt + lq * 4 + r;
            float rr = sigm(acc[0][mt][r] + bf0);
            float zz = sigm(acc[1][mt][r] + bf1);
            float nn = tanhf_(acc[2][mt][r] + bf2 + rr * (acc[3][mt][r] + bf3));
            float hold = bf2f(R[a1 + row * 136 + hc]);
            hfbuf[mt * 4 + r] = f2bf((1.f - zz) * nn + zz * hold);
          }
      }
      __syncthreads();
      // build A2 = [h_f | h] over R[0..16896)
#pragma unroll
      for (int mt = 0; mt < 4; ++mt)
#pragma unroll
        for (int r = 0; r < 4; ++r) {
          int row = 16 * mt + lq * 4 + r;
          R[row * 264 + hc] = hfbuf[mt * 4 + r];
        }
#pragma unroll
      for (int j = 0; j < 2; ++j) {
        int chunk = tid * 2 + j, row = chunk >> 4, co = (chunk & 15) * 8;
        *(s16x8*)&R[row * 264 + 128 + co] = hstage[j];
      }
      __syncthreads();
      f32x4 acc2[4] = {};
#pragma unroll
      for (int ks = 0; ks < 8; ++ks) {
        s16x8 a[4];
#pragma unroll
        for (int mt = 0; mt < 4; ++mt) a[mt] = *(const s16x8*)&R[(16 * mt + lr) * 264 + ks * 32 + lk];
#pragma unroll
        for (int mt = 0; mt < 4; ++mt) acc2[mt] = mf(a[mt], FU[ks], acc2[mt]);
      }
      __syncthreads();  // all A2 reads done before overwriting with H2
#pragma unroll
      for (int mt = 0; mt < 4; ++mt)
#pragma unroll
        for (int r = 0; r < 4; ++r) {
          int row = 16 * mt + lq * 4 + r;
          R[h2 + row * 136 + hc] = f2bf(tanhf_(acc2[mt][r] + bub));
        }
      __syncthreads();
      pred_phase(node, lev - 1, lev >= 2, Glm1, h2);
      __syncthreads();
    }
    { int t = a1; a1 = h2; h2 = t; }
  }
}

// ---------------------------------- host -------------------------------------
extern "C" void kernel_launch(void* const* d_in, const int* in_sizes, int n_in,
                              void* d_out, int out_size, void* d_ws, size_t ws_size,
                              hipStream_t stream) {
  const float* z       = (const float*)d_in[0];
  const float* z2h_w   = (const float*)d_in[1];
  const float* z2h_b   = (const float*)d_in[2];
  const float* h2o_w   = (const float*)d_in[3];
  const float* h2o_b   = (const float*)d_in[4];
  const float* anc_wi  = (const float*)d_in[5];
  const float* anc_wh  = (const float*)d_in[6];
  const float* anc_bi  = (const float*)d_in[7];
  const float* anc_bh  = (const float*)d_in[8];
  const float* frat_wi = (const float*)d_in[9];
  const float* frat_wh = (const float*)d_in[10];
  const float* frat_bi = (const float*)d_in[11];
  const float* frat_bh = (const float*)d_in[12];
  const float* ua_w    = (const float*)d_in[13];
  const float* ua_b    = (const float*)d_in[14];
  const float* uf_w    = (const float*)d_in[15];
  const float* uf_b    = (const float*)d_in[16];
  (void)in_sizes; (void)n_in; (void)out_size; (void)ws_size;

  char* ws = (char*)d_ws;
  u16* Wz    = (u16*)(ws + 0);
  u16* Wo    = (u16*)(ws + 32768);
  u16* Wanc  = (u16*)(ws + 40960);
  u16* Wfrat = (u16*)(ws + 204800);
  u16* Wu    = (u16*)(ws + 368640);
  float* Bga = (float*)(ws + 434176);
  float* Bgf = (float*)(ws + 436224);
  float* Bu  = (float*)(ws + 438272);
  u16* Gb    = (u16*)(ws + 524288);  // 5 buffers x 32768x128 bf16 = 42 MB
  float* out = (float*)d_out;

  hipLaunchKernelGGL(prep_kernel, dim3(256), dim3(256), 0, stream,
                     z2h_w, h2o_w, anc_wi, anc_wh, frat_wi, frat_wh, ua_w, uf_w,
                     anc_bi, anc_bh, frat_bi, frat_bh, ua_b, uf_b,
                     Wz, Wo, Wanc, Wfrat, Wu, Bga, Bgf, Bu);

  hipLaunchKernelGGL(tree_kernel, dim3(BATCH / 64), dim3(512), 0, stream,
                     z, Wz, Wo, Wanc, Wfrat, Wu, Bga, Bgf, Bu, z2h_b, h2o_b,
                     Gb, out);
}

// Round 5
// 1420.594 us; speedup vs baseline: 1.4213x; 1.4213x over previous
//
#include <hip/hip_runtime.h>
#include <cstddef>

// Decoder tree-GRU, MI355X gfx950. B=32768, I=H=128, O=32, DEPTH=5, ARITY=2.
// Single persistent-weight kernel: each block owns 64 batch rows for the whole
// 63-node preorder tree. FA/FF/FU weight fragments live in VGPRs (152/wave,
// cap 256 via launch_bounds(512,2)); Wo re-read from L2; probs stack in LDS;
// hidden stack in global ws. 2 dispatches total.

#define BATCH 32768

typedef float f32x4 __attribute__((ext_vector_type(4)));
typedef short s16x8 __attribute__((ext_vector_type(8)));
typedef unsigned short u16;

__device__ __forceinline__ float bf2f(u16 u){unsigned x=((unsigned)u)<<16;return __builtin_bit_cast(float,x);}
__device__ __forceinline__ u16 f2bf(float f){unsigned u=__builtin_bit_cast(unsigned,f);u+=0x7fffu+((u>>16)&1u);return (u16)(u>>16);}
__device__ __forceinline__ float sigm(float x){return 1.f/(1.f+__expf(-x));}
__device__ __forceinline__ float tanhf_(float x){return 1.f-2.f/(__expf(2.f*x)+1.f);}
__device__ __forceinline__ f32x4 mf(s16x8 a,s16x8 b,f32x4 c){return __builtin_amdgcn_mfma_f32_16x16x32_bf16(a,b,c,0,0,0);}

// Preorder schedule: step i (0-based) produces node i+1. byte = lev | (FRAT<<3).
__device__ __constant__ unsigned char SCHED[62] = {
 5,4,3,2,1,9,10,1,9,11,2,1,9,10,1,9,12,3,2,1,9,10,1,9,11,2,1,9,10,1,9,13,
 4,3,2,1,9,10,1,9,11,2,1,9,10,1,9,12,3,2,1,9,10,1,9,11,2,1,9,10,1,9};

// ---------------- prep: pack weights transposed [N][K] bf16 + fused biases ----
// Wz[128][128]=z2h_w^T ; Wo[32][128]=h2o_w^T
// Wcat[512][160]: rows 0-255 gates r,z (k<32: wi[g], k>=32: wh[g]);
//                 rows 256-383 gi_n (k<32: wi[2], else 0);
//                 rows 384-511 gh_n (k<32: 0, else wh[2])
// Wu[128][256]: k<128 uf_w^T, k>=128 ua_w^T
// Bg*[4][128] = {bi0+bh0, bi1+bh1, bi2, bh2} ; Bu[128]=uf_b+ua_b
__global__ void prep_kernel(const float* __restrict__ z2h_w, const float* __restrict__ h2o_w,
                            const float* __restrict__ anc_wi, const float* __restrict__ anc_wh,
                            const float* __restrict__ frat_wi, const float* __restrict__ frat_wh,
                            const float* __restrict__ ua_w, const float* __restrict__ uf_w,
                            const float* __restrict__ anc_bi, const float* __restrict__ anc_bh,
                            const float* __restrict__ frat_bi, const float* __restrict__ frat_bh,
                            const float* __restrict__ ua_b, const float* __restrict__ uf_b,
                            u16* __restrict__ Wz, u16* __restrict__ Wo, u16* __restrict__ Wanc,
                            u16* __restrict__ Wfrat, u16* __restrict__ Wu,
                            float* __restrict__ Bga, float* __restrict__ Bgf, float* __restrict__ Bu) {
  int tid = blockIdx.x * blockDim.x + threadIdx.x;
  int stride = gridDim.x * blockDim.x;
  for (int i = tid; i < 128 * 128; i += stride) {
    int n = i / 128, k = i % 128;
    Wz[n * 128 + k] = f2bf(z2h_w[k * 128 + n]);
  }
  for (int i = tid; i < 32 * 128; i += stride) {
    int n = i / 128, k = i % 128;
    Wo[n * 128 + k] = f2bf(h2o_w[k * 32 + n]);
  }
  for (int i = tid; i < 512 * 160; i += stride) {
    int n = i / 160, k = i % 160;
    float va, vf;
    if (n < 256) {
      int g = n >> 7, hcc = n & 127;
      if (k < 32) { va = anc_wi[g*32*128 + k*128 + hcc]; vf = frat_wi[g*32*128 + k*128 + hcc]; }
      else        { va = anc_wh[g*128*128 + (k-32)*128 + hcc]; vf = frat_wh[g*128*128 + (k-32)*128 + hcc]; }
    } else if (n < 384) {
      int hcc = n - 256;
      if (k < 32) { va = anc_wi[2*32*128 + k*128 + hcc]; vf = frat_wi[2*32*128 + k*128 + hcc]; }
      else        { va = 0.f; vf = 0.f; }
    } else {
      int hcc = n - 384;
      if (k < 32) { va = 0.f; vf = 0.f; }
      else        { va = anc_wh[2*128*128 + (k-32)*128 + hcc]; vf = frat_wh[2*128*128 + (k-32)*128 + hcc]; }
    }
    Wanc[i] = f2bf(va);
    Wfrat[i] = f2bf(vf);
  }
  for (int i = tid; i < 128 * 256; i += stride) {
    int n = i / 256, k = i % 256;
    float v = (k < 128) ? uf_w[k * 128 + n] : ua_w[(k - 128) * 128 + n];
    Wu[i] = f2bf(v);
  }
  for (int i = tid; i < 128; i += stride) {
    Bga[i]       = anc_bi[i]       + anc_bh[i];
    Bga[128 + i] = anc_bi[128 + i] + anc_bh[128 + i];
    Bga[256 + i] = anc_bi[256 + i];
    Bga[384 + i] = anc_bh[256 + i];
    Bgf[i]       = frat_bi[i]       + frat_bh[i];
    Bgf[128 + i] = frat_bi[128 + i] + frat_bh[128 + i];
    Bgf[256 + i] = frat_bi[256 + i];
    Bgf[384 + i] = frat_bh[256 + i];
    Bu[i] = uf_b[i] + ua_b[i];
  }
}

// --------------------------- persistent tree kernel ---------------------------
__global__ __launch_bounds__(512, 2) void tree_kernel(
    const float* __restrict__ z,
    const u16* __restrict__ Wz, const u16* __restrict__ Wo,
    const u16* __restrict__ Wanc, const u16* __restrict__ Wfrat, const u16* __restrict__ Wu,
    const float* __restrict__ Bga, const float* __restrict__ Bgf, const float* __restrict__ Bu,
    const float* __restrict__ z2h_b, const float* __restrict__ h2o_b,
    u16* __restrict__ Gb, float* __restrict__ out) {
  // R: two 64x136 bf16 h-buffers (A1h / H2, swapped each step); A2 [64][264]
  // overlays R[0..16896) during FRAT. PRs: 6-level probs stack [64][40] each.
  __shared__ u16 R[17408];
  __shared__ u16 PRs[15360];
  const int tid = threadIdx.x;
  const int w = tid >> 6, l = tid & 63, lr = l & 15, lq = l >> 4, lk = lq * 8;
  const int hc = 16 * w + lr;         // this lane's hidden column (8-way N split)
  const size_t brow = (size_t)blockIdx.x * 64;
  const size_t GSTR = (size_t)BATCH * 128;

  // ---- persistent weight fragments: FA/FF (gates), FU (uf|ua). 152 VGPRs ----
  s16x8 FA[15], FF[15], FU[8];
#pragma unroll
  for (int j = 0; j < 15; ++j) {
    const int gb = (j < 5) ? 0 : ((j < 10) ? 1 : ((j < 11) ? 2 : 3));
    const int ks = (j < 5) ? j : ((j < 10) ? (j - 5) : ((j < 11) ? 0 : (j - 10)));
    const size_t off = (size_t)(128 * gb + hc) * 160 + ks * 32 + lk;
    FA[j] = *(const s16x8*)&Wanc[off];
    FF[j] = *(const s16x8*)&Wfrat[off];
  }
#pragma unroll
  for (int ks = 0; ks < 8; ++ks) FU[ks] = *(const s16x8*)&Wu[(size_t)hc * 256 + ks * 32 + lk];
  const float ba0 = Bga[hc], ba1 = Bga[128 + hc], ba2 = Bga[256 + hc], ba3 = Bga[384 + hc];
  const float bf0 = Bgf[hc], bf1 = Bgf[128 + hc], bf2 = Bgf[256 + hc], bf3 = Bgf[384 + hc];
  const float bub = Bu[hc];
  const float bz = z2h_b[hc];
  const float bo0 = h2o_b[lr], bo1 = h2o_b[16 + lr];

  int a1 = 0, h2 = 8704;  // u16 offsets of the two h-buffers in R

  // pred (waves 4-7; Wo B-frags re-read from global = L2-hot) and H2->G copy
  // (waves 0-3). Caller barriers around this.
  auto pred_phase = [&](int node, int levC, bool doG, u16* Gdst, int hb, bool wantSM) {
    if (w >= 4) {
      const int m = w - 4;
      f32x4 p0 = {}, p1 = {};
#pragma unroll
      for (int ks = 0; ks < 4; ++ks) {
        s16x8 a = *(const s16x8*)&R[hb + (16 * m + lr) * 136 + ks * 32 + lk];
        s16x8 b0 = *(const s16x8*)&Wo[(size_t)lr * 128 + ks * 32 + lk];
        s16x8 b1 = *(const s16x8*)&Wo[(size_t)(16 + lr) * 128 + ks * 32 + lk];
        p0 = mf(a, b0, p0);
        p1 = mf(a, b1, p1);
      }
      float* op = out + ((size_t)node * BATCH + brow) * 32;
#pragma unroll
      for (int r = 0; r < 4; ++r) {
        int row = 16 * m + lq * 4 + r;
        float v0 = p0[r] + bo0, v1 = p1[r] + bo1;
        __builtin_nontemporal_store(v0, &op[row * 32 + lr]);
        __builtin_nontemporal_store(v1, &op[row * 32 + 16 + lr]);
        if (wantSM) {
          float mx = fmaxf(v0, v1);
#pragma unroll
          for (int o = 1; o < 16; o <<= 1) mx = fmaxf(mx, __shfl_xor(mx, o));
          float e0 = __expf(v0 - mx), e1 = __expf(v1 - mx);
          float s = e0 + e1;
#pragma unroll
          for (int o = 1; o < 16; o <<= 1) s += __shfl_xor(s, o);
          float inv = 1.f / s;
          PRs[levC * 2560 + row * 40 + lr] = f2bf(e0 * inv);
          PRs[levC * 2560 + row * 40 + 16 + lr] = f2bf(e1 * inv);
        }
      }
    } else if (doG) {
#pragma unroll
      for (int j = 0; j < 4; ++j) {
        int chunk = (w * 64 + l) + 256 * j, row = chunk >> 4, co = (chunk & 15) * 8;
        *(s16x8*)&Gdst[(brow + row) * 128 + co] = *(const s16x8*)&R[hb + row * 136 + co];
      }
    }
  };

  // ---------------- init: h0 = z@Wz+b -> H2, G[5]; pred node 0 ----------------
  {
    int row = tid >> 3, seg = tid & 7;
    const float* src = z + (brow + row) * 128 + seg * 16;
    u16* dst = &R[a1 + row * 136 + seg * 16];
#pragma unroll
    for (int k = 0; k < 16; ++k) dst[k] = f2bf(src[k]);
  }
  __syncthreads();
  {
    f32x4 acc0[4] = {};
#pragma unroll
    for (int ks = 0; ks < 4; ++ks) {
      s16x8 b = *(const s16x8*)&Wz[(size_t)hc * 128 + ks * 32 + lk];
      s16x8 a[4];
#pragma unroll
      for (int mt = 0; mt < 4; ++mt) a[mt] = *(const s16x8*)&R[a1 + (16 * mt + lr) * 136 + ks * 32 + lk];
#pragma unroll
      for (int mt = 0; mt < 4; ++mt) acc0[mt] = mf(a[mt], b, acc0[mt]);
    }
#pragma unroll
    for (int mt = 0; mt < 4; ++mt)
#pragma unroll
      for (int r = 0; r < 4; ++r) {
        int row = 16 * mt + lq * 4 + r;
        R[h2 + row * 136 + hc] = f2bf(acc0[mt][r] + bz);
      }
  }
  __syncthreads();
  pred_phase(0, 5, true, Gb + 4 * GSTR, h2, true);
  __syncthreads();
  { int t = a1; a1 = h2; h2 = t; }

  // ------------------------------- 62 tree steps ------------------------------
  for (int i = 0; i < 62; ++i) {
    const int sc = SCHED[i];
    const int lev = sc & 7;
    const bool isF = (sc & 8) != 0;
    const int node = i + 1;
    u16* Glm1 = Gb + (size_t)((lev >= 2) ? (lev - 2) : 0) * GSTR;  // G[lev-1]
    u16* Glv  = Gb + (size_t)(lev - 1) * GSTR;                      // G[lev]

    if (!isF) {
      // ====== ANC: h in A1h (prev H2), probs in PR[lev] -> h_ai ======
      // mt-half processing keeps acc at 32 VGPRs (4 gates x 2 tiles).
#pragma unroll
      for (int half = 0; half < 2; ++half) {
        f32x4 acc[4][2] = {};
        {
          s16x8 a[2];
#pragma unroll
          for (int m2 = 0; m2 < 2; ++m2)
            a[m2] = *(const s16x8*)&PRs[lev * 2560 + (16 * (2 * half + m2) + lr) * 40 + lk];
#pragma unroll
          for (int m2 = 0; m2 < 2; ++m2) {
            acc[0][m2] = mf(a[m2], FA[0], acc[0][m2]);
            acc[1][m2] = mf(a[m2], FA[5], acc[1][m2]);
            acc[2][m2] = mf(a[m2], FA[10], acc[2][m2]);
          }
        }
#pragma unroll
        for (int ks = 1; ks < 5; ++ks) {
          s16x8 a[2];
#pragma unroll
          for (int m2 = 0; m2 < 2; ++m2)
            a[m2] = *(const s16x8*)&R[a1 + (16 * (2 * half + m2) + lr) * 136 + (ks - 1) * 32 + lk];
#pragma unroll
          for (int m2 = 0; m2 < 2; ++m2) {
            acc[0][m2] = mf(a[m2], FA[ks], acc[0][m2]);
            acc[1][m2] = mf(a[m2], FA[5 + ks], acc[1][m2]);
            acc[3][m2] = mf(a[m2], FA[10 + ks], acc[3][m2]);
          }
        }
#pragma unroll
        for (int m2 = 0; m2 < 2; ++m2)
#pragma unroll
          for (int r = 0; r < 4; ++r) {
            int row = 16 * (2 * half + m2) + lq * 4 + r;
            float rr = sigm(acc[0][m2][r] + ba0);
            float zz = sigm(acc[1][m2][r] + ba1);
            float nn = tanhf_(acc[2][m2][r] + ba2 + rr * (acc[3][m2][r] + ba3));
            float hold = bf2f(R[a1 + row * 136 + hc]);
            R[h2 + row * 136 + hc] = f2bf((1.f - zz) * nn + zz * hold);
          }
      }
      __syncthreads();
      pred_phase(node, lev - 1, lev >= 2, Glm1, h2, true);
      __syncthreads();
    } else {
      // ====== FRAT: h_f = GRU(PR[lev-1], h_ai); h2n = tanh(h_f@uf + h@ua) ======
      s16x8 hstage[2];  // prefetch h = G[lev] for the ua matmul
#pragma unroll
      for (int j = 0; j < 2; ++j) {
        int chunk = tid * 2 + j, row = chunk >> 4, co = (chunk & 15) * 8;
        hstage[j] = *(const s16x8*)&Glv[(brow + row) * 128 + co];
      }
      if (lev >= 2) {  // h_ai not in LDS: stage from G[lev-1]
#pragma unroll
        for (int j = 0; j < 2; ++j) {
          int chunk = tid * 2 + j, row = chunk >> 4, co = (chunk & 15) * 8;
          *(s16x8*)&R[a1 + row * 136 + co] = *(const s16x8*)&Glm1[(brow + row) * 128 + co];
        }
      }
      __syncthreads();
      u16 hfbuf[16];
#pragma unroll
      for (int half = 0; half < 2; ++half) {
        f32x4 acc[4][2] = {};
        {
          s16x8 a[2];
#pragma unroll
          for (int m2 = 0; m2 < 2; ++m2)
            a[m2] = *(const s16x8*)&PRs[(lev - 1) * 2560 + (16 * (2 * half + m2) + lr) * 40 + lk];
#pragma unroll
          for (int m2 = 0; m2 < 2; ++m2) {
            acc[0][m2] = mf(a[m2], FF[0], acc[0][m2]);
            acc[1][m2] = mf(a[m2], FF[5], acc[1][m2]);
            acc[2][m2] = mf(a[m2], FF[10], acc[2][m2]);
          }
        }
#pragma unroll
        for (int ks = 1; ks < 5; ++ks) {
          s16x8 a[2];
#pragma unroll
          for (int m2 = 0; m2 < 2; ++m2)
            a[m2] = *(const s16x8*)&R[a1 + (16 * (2 * half + m2) + lr) * 136 + (ks - 1) * 32 + lk];
#pragma unroll
          for (int m2 = 0; m2 < 2; ++m2) {
            acc[0][m2] = mf(a[m2], FF[ks], acc[0][m2]);
            acc[1][m2] = mf(a[m2], FF[5 + ks], acc[1][m2]);
            acc[3][m2] = mf(a[m2], FF[10 + ks], acc[3][m2]);
          }
        }
#pragma unroll
        for (int m2 = 0; m2 < 2; ++m2)
#pragma unroll
          for (int r = 0; r < 4; ++r) {
            int row = 16 * (2 * half + m2) + lq * 4 + r;
            float rr = sigm(acc[0][m2][r] + bf0);
            float zz = sigm(acc[1][m2][r] + bf1);
            float nn = tanhf_(acc[2][m2][r] + bf2 + rr * (acc[3][m2][r] + bf3));
            float hold = bf2f(R[a1 + row * 136 + hc]);
            hfbuf[(2 * half + m2) * 4 + r] = f2bf((1.f - zz) * nn + zz * hold);
          }
      }
      __syncthreads();
      // build A2 = [h_f | h] over R[0..16896)
#pragma unroll
      for (int mt = 0; mt < 4; ++mt)
#pragma unroll
        for (int r = 0; r < 4; ++r) {
          int row = 16 * mt + lq * 4 + r;
          R[row * 264 + hc] = hfbuf[mt * 4 + r];
        }
#pragma unroll
      for (int j = 0; j < 2; ++j) {
        int chunk = tid * 2 + j, row = chunk >> 4, co = (chunk & 15) * 8;
        *(s16x8*)&R[row * 264 + 128 + co] = hstage[j];
      }
      __syncthreads();
      f32x4 acc2[4] = {};
#pragma unroll
      for (int ks = 0; ks < 8; ++ks) {
        s16x8 a[4];
#pragma unroll
        for (int mt = 0; mt < 4; ++mt) a[mt] = *(const s16x8*)&R[(16 * mt + lr) * 264 + ks * 32 + lk];
#pragma unroll
        for (int mt = 0; mt < 4; ++mt) acc2[mt] = mf(a[mt], FU[ks], acc2[mt]);
      }
      __syncthreads();  // all A2 reads done before overwriting with H2
#pragma unroll
      for (int mt = 0; mt < 4; ++mt)
#pragma unroll
        for (int r = 0; r < 4; ++r) {
          int row = 16 * mt + lq * 4 + r;
          R[h2 + row * 136 + hc] = f2bf(tanhf_(acc2[mt][r] + bub));
        }
      __syncthreads();
      pred_phase(node, lev - 1, lev >= 2, Glm1, h2, lev >= 2);
      __syncthreads();
    }
    { int t = a1; a1 = h2; h2 = t; }
  }
}

// ---------------------------------- host -------------------------------------
extern "C" void kernel_launch(void* const* d_in, const int* in_sizes, int n_in,
                              void* d_out, int out_size, void* d_ws, size_t ws_size,
                              hipStream_t stream) {
  const float* z       = (const float*)d_in[0];
  const float* z2h_w   = (const float*)d_in[1];
  const float* z2h_b   = (const float*)d_in[2];
  const float* h2o_w   = (const float*)d_in[3];
  const float* h2o_b   = (const float*)d_in[4];
  const float* anc_wi  = (const float*)d_in[5];
  const float* anc_wh  = (const float*)d_in[6];
  const float* anc_bi  = (const float*)d_in[7];
  const float* anc_bh  = (const float*)d_in[8];
  const float* frat_wi = (const float*)d_in[9];
  const float* frat_wh = (const float*)d_in[10];
  const float* frat_bi = (const float*)d_in[11];
  const float* frat_bh = (const float*)d_in[12];
  const float* ua_w    = (const float*)d_in[13];
  const float* ua_b    = (const float*)d_in[14];
  const float* uf_w    = (const float*)d_in[15];
  const float* uf_b    = (const float*)d_in[16];
  (void)in_sizes; (void)n_in; (void)out_size; (void)ws_size;

  char* ws = (char*)d_ws;
  u16* Wz    = (u16*)(ws + 0);
  u16* Wo    = (u16*)(ws + 32768);
  u16* Wanc  = (u16*)(ws + 40960);
  u16* Wfrat = (u16*)(ws + 204800);
  u16* Wu    = (u16*)(ws + 368640);
  float* Bga = (float*)(ws + 434176);
  float* Bgf = (float*)(ws + 436224);
  float* Bu  = (float*)(ws + 438272);
  u16* Gb    = (u16*)(ws + 524288);  // 5 buffers x 32768x128 bf16 = 42 MB
  float* out = (float*)d_out;

  hipLaunchKernelGGL(prep_kernel, dim3(256), dim3(256), 0, stream,
                     z2h_w, h2o_w, anc_wi, anc_wh, frat_wi, frat_wh, ua_w, uf_w,
                     anc_bi, anc_bh, frat_bi, frat_bh, ua_b, uf_b,
                     Wz, Wo, Wanc, Wfrat, Wu, Bga, Bgf, Bu);

  hipLaunchKernelGGL(tree_kernel, dim3(BATCH / 64), dim3(512), 0, stream,
                     z, Wz, Wo, Wanc, Wfrat, Wu, Bga, Bgf, Bu, z2h_b, h2o_b,
                     Gb, out);
}